// Round 8
// baseline (55.386 us; speedup 1.0000x reference)
//
#include <hip/hip_runtime.h>

// PopulationAttention: out = (Q K^T / sqrt(64)) @ (V * x)
// No softmax => associativity: out = Q @ M, M = K^T @ (V*x) / 8  (64x64 per head)
// B=4, H=16, N=2048, D=64  -> BH=64 batched heads.
//
// 3 kernels, coherence via kernel boundaries only (R2: per-block
// __threadfence = 4x regression on CDNA4 non-coherent XCD L2s).
// Empirical record:
//   kv streaming NCH16 (1024 blk, unroll4, shfl-x): ~7 us      [R6 bench]
//   red: ~3 us                                                  [R6 bench]
//   qm 8x8 tile / 256 rows / unroll2: ~19 us incl 128KB/blk
//      partial-reduce prologue                                  [R5 bench]
//   qm 4x8 tile / 128 rows / unroll4: ~42 us (reg/sched bloat)  [R7 bench]
//   qm manual double-buffer: 256 VGPR, 72 us                    [R6 bench]
// This round: proven qm body + cheap Mbuf prologue (16KB instead of 128KB).

#define BH 64
#define NROWS 2048
#define DIM 64
#define NCH 16                        // stage-A chunks/head; partial = 16 MB
#define ROWS_PER_CH (NROWS / NCH)     // 128
#define ROWS_PER_WV (ROWS_PER_CH / 4) // 32

// ---- Stage A: partial[bh][ch] = sum_{m in slice} K[m]^T (V[m]*x[m]) ----
// [UNCHANGED — proven ~7 us]
__global__ __launch_bounds__(256) void popattn_kv(
    const float* __restrict__ K, const float* __restrict__ V,
    const float* __restrict__ x, float* __restrict__ partial) {
  const int ch = blockIdx.x;
  const int bh = blockIdx.y;
  const float* Kp = K + (size_t)bh * (NROWS * DIM);
  const float* Vp = V + (size_t)bh * (NROWS * DIM);
  const float* xp = x + (size_t)(bh >> 4) * NROWS;  // x is [B,1,N,1], b = bh/16

  const int t = threadIdx.x;
  const int wv = t >> 6;          // wave id 0..3
  const int l = t & 63;
  const int ti = (l >> 3) << 3;   // 8x8 tile row base (K column block)
  const int tj = (l & 7) << 3;    // 8x8 tile col base (V column block)

  const int mstart = ch * ROWS_PER_CH + wv * ROWS_PER_WV;
  // lane L holds x[mstart + (L&31)]; broadcast per-m via __shfl.
  const float xall = xp[mstart + (l & 31)];

  float acc[8][8];
#pragma unroll
  for (int i = 0; i < 8; ++i)
#pragma unroll
    for (int j = 0; j < 8; ++j) acc[i][j] = 0.f;

#pragma unroll 4
  for (int mi = 0; mi < ROWS_PER_WV; ++mi) {
    const int m = mstart + mi;
    const float4 k0 = *(const float4*)(Kp + (size_t)m * DIM + ti);
    const float4 k1 = *(const float4*)(Kp + (size_t)m * DIM + ti + 4);
    const float4 v0 = *(const float4*)(Vp + (size_t)m * DIM + tj);
    const float4 v1 = *(const float4*)(Vp + (size_t)m * DIM + tj + 4);
    const float xv = __shfl(xall, mi);
    const float kk[8] = {k0.x, k0.y, k0.z, k0.w, k1.x, k1.y, k1.z, k1.w};
    float vw[8] = {v0.x, v0.y, v0.z, v0.w, v1.x, v1.y, v1.z, v1.w};
#pragma unroll
    for (int j = 0; j < 8; ++j) vw[j] *= xv;
#pragma unroll
    for (int i = 0; i < 8; ++i)
#pragma unroll
      for (int j = 0; j < 8; ++j) acc[i][j] += kk[i] * vw[j];
  }

  // ---- cross-wave reduce in LDS, fixed order s=0..3 (deterministic) ----
  __shared__ float smem[DIM * DIM];  // 16 KB
#pragma unroll 1
  for (int s = 0; s < 4; ++s) {
    if (wv == s) {
#pragma unroll
      for (int ii = 0; ii < 8; ++ii) {
        float* dst = &smem[(ti + ii) * DIM + tj];
        if (s == 0) {
          float4 o;
          o.x = acc[ii][0]; o.y = acc[ii][1]; o.z = acc[ii][2]; o.w = acc[ii][3];
          *(float4*)dst = o;
          o.x = acc[ii][4]; o.y = acc[ii][5]; o.z = acc[ii][6]; o.w = acc[ii][7];
          *(float4*)(dst + 4) = o;
        } else {
          float4 a = *(float4*)dst;
          a.x += acc[ii][0]; a.y += acc[ii][1]; a.z += acc[ii][2]; a.w += acc[ii][3];
          *(float4*)dst = a;
          a = *(float4*)(dst + 4);
          a.x += acc[ii][4]; a.y += acc[ii][5]; a.z += acc[ii][6]; a.w += acc[ii][7];
          *(float4*)(dst + 4) = a;
        }
      }
    }
    __syncthreads();
  }

  float* Pp = partial + ((size_t)bh * NCH + ch) * (DIM * DIM);
#pragma unroll
  for (int i = 0; i < 4; ++i) {
    const int idx = (t + 256 * i) * 4;
    *(float4*)(Pp + idx) = *(const float4*)&smem[idx];
  }
}

// ---- Stage A2: M[bh] = (sum_c partial[bh][c]) * 0.125, fixed order ----
// [UNCHANGED — proven ~3 us]
__global__ __launch_bounds__(256) void popattn_red(
    const float* __restrict__ partial, float* __restrict__ M) {
  const int e = blockIdx.x;   // 0..3 quarter of the 64x64 matrix
  const int bh = blockIdx.y;
  const int off = e * 1024 + threadIdx.x * 4;
  const float* Pp = partial + (size_t)bh * NCH * (DIM * DIM);
  float sx = 0.f, sy = 0.f, sz = 0.f, sw = 0.f;
#pragma unroll
  for (int c = 0; c < NCH; ++c) {
    const float4 p = *(const float4*)(Pp + (size_t)c * (DIM * DIM) + off);
    sx += p.x; sy += p.y; sz += p.z; sw += p.w;
  }
  float4 o;
  o.x = sx * 0.125f; o.y = sy * 0.125f; o.z = sz * 0.125f; o.w = sw * 0.125f;
  *(float4*)(M + (size_t)bh * (DIM * DIM) + off) = o;
}

// ---- Stage B: out[bh] = Q[bh] @ M[bh]. 256 rows/block, 8x8 tile, unroll 2.
// [Body proven ~19 us WITH a 128KB/block reduce prologue (R5 bench); here the
//  prologue is a 16KB Mbuf read -> predict 14-16 us.] ----
__global__ __launch_bounds__(256) void popattn_qm(
    const float* __restrict__ Q, const float* __restrict__ M,
    float* __restrict__ out) {
  const int ch = blockIdx.x;  // 0..7
  const int bh = blockIdx.y;
  const int row0 = ch * 256;
  const float* Qp = Q + (size_t)bh * (NROWS * DIM) + (size_t)row0 * DIM;
  float* Op = out + (size_t)bh * (NROWS * DIM) + (size_t)row0 * DIM;

  __shared__ float sM[DIM * DIM];  // 16 KB

  const int t = threadIdx.x;
  {
    const float* Mp = M + (size_t)bh * (DIM * DIM);
#pragma unroll
    for (int i = 0; i < 4; ++i) {
      const int off = i * 1024 + t * 4;
      *(float4*)&sM[off] = *(const float4*)(Mp + off);
    }
  }
  __syncthreads();

  const int r = t >> 3;         // rows r + 32*rr, rr = 0..7
  const int c8 = (t & 7) * 8;   // cols c8..c8+7

  float acc[8][8];
#pragma unroll
  for (int rr = 0; rr < 8; ++rr)
#pragma unroll
    for (int jj = 0; jj < 8; ++jj) acc[rr][jj] = 0.f;

#pragma unroll 2
  for (int kg = 0; kg < 16; ++kg) {
    float4 qv[8];
#pragma unroll
    for (int rr = 0; rr < 8; ++rr)
      qv[rr] = *(const float4*)(Qp + (size_t)(r + 32 * rr) * DIM + kg * 4);
#pragma unroll
    for (int dk = 0; dk < 4; ++dk) {
      const int k = kg * 4 + dk;
      const float4 m0 = *(const float4*)&sM[k * DIM + c8];
      const float4 m1 = *(const float4*)&sM[k * DIM + c8 + 4];
      const float mm[8] = {m0.x, m0.y, m0.z, m0.w, m1.x, m1.y, m1.z, m1.w};
#pragma unroll
      for (int rr = 0; rr < 8; ++rr) {
        const float q = (dk == 0) ? qv[rr].x : (dk == 1) ? qv[rr].y
                       : (dk == 2) ? qv[rr].z : qv[rr].w;
#pragma unroll
        for (int jj = 0; jj < 8; ++jj) acc[rr][jj] += q * mm[jj];
      }
    }
  }

#pragma unroll
  for (int rr = 0; rr < 8; ++rr) {
    float4 o;
    o.x = acc[rr][0]; o.y = acc[rr][1]; o.z = acc[rr][2]; o.w = acc[rr][3];
    *(float4*)(Op + (size_t)(r + 32 * rr) * DIM + c8) = o;
    o.x = acc[rr][4]; o.y = acc[rr][5]; o.z = acc[rr][6]; o.w = acc[rr][7];
    *(float4*)(Op + (size_t)(r + 32 * rr) * DIM + c8 + 4) = o;
  }
}

extern "C" void kernel_launch(void* const* d_in, const int* in_sizes, int n_in,
                              void* d_out, int out_size, void* d_ws, size_t ws_size,
                              hipStream_t stream) {
  const float* Q = (const float*)d_in[0];
  const float* K = (const float*)d_in[1];
  const float* V = (const float*)d_in[2];
  const float* x = (const float*)d_in[3];
  float* out = (float*)d_out;
  float* partial = (float*)d_ws;  // BH*NCH*4096 floats = 16 MB
  float* Mbuf = partial + (size_t)BH * NCH * DIM * DIM;  // +1 MB

  dim3 blk(256);
  popattn_kv<<<dim3(NCH, BH), blk, 0, stream>>>(K, V, x, partial);
  popattn_red<<<dim3(4, BH), blk, 0, stream>>>(partial, Mbuf);
  popattn_qm<<<dim3(NROWS / 256, BH), blk, 0, stream>>>(Q, Mbuf, out);
}

// Round 9
// 54.680 us; speedup vs baseline: 1.0129x; 1.0129x over previous
//
#include <hip/hip_runtime.h>

// PopulationAttention: out = (Q K^T / sqrt(64)) @ (V * x)
// No softmax => associativity: out = Q @ M, M = K^T @ (V*x) / 8  (64x64 per head)
// B=4, H=16, N=2048, D=64  -> BH=64 batched heads.
//
// 3 kernels, coherence via kernel boundaries only (R2: per-block
// __threadfence = 4x regression on CDNA4 non-coherent XCD L2s).
// Empirical record:
//   kv streaming NCH16 (1024 blk, unroll4, shfl-x): ~7 us        [R6/R7/R8]
//   red: ~3 us                                                    [R6/R7/R8]
//   qm 8x8/256rows/unroll2 + __launch_bounds__(256,2): ~18 us     [R5 bench]
//   qm same body, NO min-waves arg: ~43 us                        [R8 bench]
//   qm manual double-buffer: 256 VGPR, 72 us                      [R6 bench]
// Lesson: this qm body NEEDS launch_bounds(256,2) to cap VGPR<=128; without
// it the allocator balloons registers and the 512-block kernel goes
// latency-bound. This round: proven-18us qm (incl. the ,2) + 16KB Mbuf
// prologue instead of the 128KB partial-reduce prologue.

#define BH 64
#define NROWS 2048
#define DIM 64
#define NCH 16                        // stage-A chunks/head; partial = 16 MB
#define ROWS_PER_CH (NROWS / NCH)     // 128
#define ROWS_PER_WV (ROWS_PER_CH / 4) // 32

// ---- Stage A: partial[bh][ch] = sum_{m in slice} K[m]^T (V[m]*x[m]) ----
// [UNCHANGED — proven ~7 us]
__global__ __launch_bounds__(256) void popattn_kv(
    const float* __restrict__ K, const float* __restrict__ V,
    const float* __restrict__ x, float* __restrict__ partial) {
  const int ch = blockIdx.x;
  const int bh = blockIdx.y;
  const float* Kp = K + (size_t)bh * (NROWS * DIM);
  const float* Vp = V + (size_t)bh * (NROWS * DIM);
  const float* xp = x + (size_t)(bh >> 4) * NROWS;  // x is [B,1,N,1], b = bh/16

  const int t = threadIdx.x;
  const int wv = t >> 6;          // wave id 0..3
  const int l = t & 63;
  const int ti = (l >> 3) << 3;   // 8x8 tile row base (K column block)
  const int tj = (l & 7) << 3;    // 8x8 tile col base (V column block)

  const int mstart = ch * ROWS_PER_CH + wv * ROWS_PER_WV;
  // lane L holds x[mstart + (L&31)]; broadcast per-m via __shfl.
  const float xall = xp[mstart + (l & 31)];

  float acc[8][8];
#pragma unroll
  for (int i = 0; i < 8; ++i)
#pragma unroll
    for (int j = 0; j < 8; ++j) acc[i][j] = 0.f;

#pragma unroll 4
  for (int mi = 0; mi < ROWS_PER_WV; ++mi) {
    const int m = mstart + mi;
    const float4 k0 = *(const float4*)(Kp + (size_t)m * DIM + ti);
    const float4 k1 = *(const float4*)(Kp + (size_t)m * DIM + ti + 4);
    const float4 v0 = *(const float4*)(Vp + (size_t)m * DIM + tj);
    const float4 v1 = *(const float4*)(Vp + (size_t)m * DIM + tj + 4);
    const float xv = __shfl(xall, mi);
    const float kk[8] = {k0.x, k0.y, k0.z, k0.w, k1.x, k1.y, k1.z, k1.w};
    float vw[8] = {v0.x, v0.y, v0.z, v0.w, v1.x, v1.y, v1.z, v1.w};
#pragma unroll
    for (int j = 0; j < 8; ++j) vw[j] *= xv;
#pragma unroll
    for (int i = 0; i < 8; ++i)
#pragma unroll
      for (int j = 0; j < 8; ++j) acc[i][j] += kk[i] * vw[j];
  }

  // ---- cross-wave reduce in LDS, fixed order s=0..3 (deterministic) ----
  __shared__ float smem[DIM * DIM];  // 16 KB
#pragma unroll 1
  for (int s = 0; s < 4; ++s) {
    if (wv == s) {
#pragma unroll
      for (int ii = 0; ii < 8; ++ii) {
        float* dst = &smem[(ti + ii) * DIM + tj];
        if (s == 0) {
          float4 o;
          o.x = acc[ii][0]; o.y = acc[ii][1]; o.z = acc[ii][2]; o.w = acc[ii][3];
          *(float4*)dst = o;
          o.x = acc[ii][4]; o.y = acc[ii][5]; o.z = acc[ii][6]; o.w = acc[ii][7];
          *(float4*)(dst + 4) = o;
        } else {
          float4 a = *(float4*)dst;
          a.x += acc[ii][0]; a.y += acc[ii][1]; a.z += acc[ii][2]; a.w += acc[ii][3];
          *(float4*)dst = a;
          a = *(float4*)(dst + 4);
          a.x += acc[ii][4]; a.y += acc[ii][5]; a.z += acc[ii][6]; a.w += acc[ii][7];
          *(float4*)(dst + 4) = a;
        }
      }
    }
    __syncthreads();
  }

  float* Pp = partial + ((size_t)bh * NCH + ch) * (DIM * DIM);
#pragma unroll
  for (int i = 0; i < 4; ++i) {
    const int idx = (t + 256 * i) * 4;
    *(float4*)(Pp + idx) = *(const float4*)&smem[idx];
  }
}

// ---- Stage A2: M[bh] = (sum_c partial[bh][c]) * 0.125, fixed order ----
// [UNCHANGED — proven ~3 us]
__global__ __launch_bounds__(256) void popattn_red(
    const float* __restrict__ partial, float* __restrict__ M) {
  const int e = blockIdx.x;   // 0..3 quarter of the 64x64 matrix
  const int bh = blockIdx.y;
  const int off = e * 1024 + threadIdx.x * 4;
  const float* Pp = partial + (size_t)bh * NCH * (DIM * DIM);
  float sx = 0.f, sy = 0.f, sz = 0.f, sw = 0.f;
#pragma unroll
  for (int c = 0; c < NCH; ++c) {
    const float4 p = *(const float4*)(Pp + (size_t)c * (DIM * DIM) + off);
    sx += p.x; sy += p.y; sz += p.z; sw += p.w;
  }
  float4 o;
  o.x = sx * 0.125f; o.y = sy * 0.125f; o.z = sz * 0.125f; o.w = sw * 0.125f;
  *(float4*)(M + (size_t)bh * (DIM * DIM) + off) = o;
}

// ---- Stage B: out[bh] = Q[bh] @ M[bh]. 256 rows/block, 8x8 tile, unroll 2.
// __launch_bounds__(256, 2) is REQUIRED (caps VGPR<=128; proven 18us vs
// 43us without it). ----
__global__ __launch_bounds__(256, 2) void popattn_qm(
    const float* __restrict__ Q, const float* __restrict__ M,
    float* __restrict__ out) {
  const int ch = blockIdx.x;  // 0..7
  const int bh = blockIdx.y;
  const int row0 = ch * 256;
  const float* Qp = Q + (size_t)bh * (NROWS * DIM) + (size_t)row0 * DIM;
  float* Op = out + (size_t)bh * (NROWS * DIM) + (size_t)row0 * DIM;

  __shared__ float sM[DIM * DIM];  // 16 KB

  const int t = threadIdx.x;
  {
    const float* Mp = M + (size_t)bh * (DIM * DIM);
#pragma unroll
    for (int i = 0; i < 4; ++i) {
      const int off = i * 1024 + t * 4;
      *(float4*)&sM[off] = *(const float4*)(Mp + off);
    }
  }
  __syncthreads();

  const int r = t >> 3;         // rows r + 32*rr, rr = 0..7
  const int c8 = (t & 7) * 8;   // cols c8..c8+7

  float acc[8][8];
#pragma unroll
  for (int rr = 0; rr < 8; ++rr)
#pragma unroll
    for (int jj = 0; jj < 8; ++jj) acc[rr][jj] = 0.f;

#pragma unroll 2
  for (int kg = 0; kg < 16; ++kg) {
    float4 qv[8];
#pragma unroll
    for (int rr = 0; rr < 8; ++rr)
      qv[rr] = *(const float4*)(Qp + (size_t)(r + 32 * rr) * DIM + kg * 4);
#pragma unroll
    for (int dk = 0; dk < 4; ++dk) {
      const int k = kg * 4 + dk;
      const float4 m0 = *(const float4*)&sM[k * DIM + c8];
      const float4 m1 = *(const float4*)&sM[k * DIM + c8 + 4];
      const float mm[8] = {m0.x, m0.y, m0.z, m0.w, m1.x, m1.y, m1.z, m1.w};
#pragma unroll
      for (int rr = 0; rr < 8; ++rr) {
        const float q = (dk == 0) ? qv[rr].x : (dk == 1) ? qv[rr].y
                       : (dk == 2) ? qv[rr].z : qv[rr].w;
#pragma unroll
        for (int jj = 0; jj < 8; ++jj) acc[rr][jj] += q * mm[jj];
      }
    }
  }

#pragma unroll
  for (int rr = 0; rr < 8; ++rr) {
    float4 o;
    o.x = acc[rr][0]; o.y = acc[rr][1]; o.z = acc[rr][2]; o.w = acc[rr][3];
    *(float4*)(Op + (size_t)(r + 32 * rr) * DIM + c8) = o;
    o.x = acc[rr][4]; o.y = acc[rr][5]; o.z = acc[rr][6]; o.w = acc[rr][7];
    *(float4*)(Op + (size_t)(r + 32 * rr) * DIM + c8 + 4) = o;
  }
}

extern "C" void kernel_launch(void* const* d_in, const int* in_sizes, int n_in,
                              void* d_out, int out_size, void* d_ws, size_t ws_size,
                              hipStream_t stream) {
  const float* Q = (const float*)d_in[0];
  const float* K = (const float*)d_in[1];
  const float* V = (const float*)d_in[2];
  const float* x = (const float*)d_in[3];
  float* out = (float*)d_out;
  float* partial = (float*)d_ws;  // BH*NCH*4096 floats = 16 MB
  float* Mbuf = partial + (size_t)BH * NCH * DIM * DIM;  // +1 MB

  dim3 blk(256);
  popattn_kv<<<dim3(NCH, BH), blk, 0, stream>>>(K, V, x, partial);
  popattn_red<<<dim3(4, BH), blk, 0, stream>>>(partial, Mbuf);
  popattn_qm<<<dim3(NROWS / 256, BH), blk, 0, stream>>>(Q, Mbuf, out);
}

// Round 10
// 49.282 us; speedup vs baseline: 1.1239x; 1.1095x over previous
//
#include <hip/hip_runtime.h>

// PopulationAttention: out = (Q K^T / sqrt(64)) @ (V * x)
// No softmax => associativity: out = Q @ M, M = K^T @ (V*x) / 8  (64x64 per head)
// B=4, H=16, N=2048, D=64  -> BH=64 batched heads.
//
// 3 kernels, coherence via kernel boundaries only (R2-bench: per-block
// __threadfence = 4x regression on CDNA4 non-coherent XCD L2s).
//
// Empirical record (TIMED totals, the only reliable metric — rocprof
// per-dispatch durations are pessimistic for L3-resident replays):
//   44.2 us  kv_staged16 + red + qm64rows/2x8tile/2048blk      [R2-proposed]
//   52-55 us any qm with 512-1024 blocks & 32-64 acc VGPRs (latency-bound
//            ~43 us regardless of launch_bounds / unroll / prologue)
//   ~10 us   kv_stream16 + red combined (timed, via R6's direct 72us qm)
// Design rule proven by the record: stage B wants MANY BLOCKS + SMALL TILES
// (occupancy/TLP), not big register tiles (ILP).
// This round = R2 config with ONE change: kv_staged16 -> kv_stream16.

#define BH 64
#define NROWS 2048
#define DIM 64
#define NCH 16                        // stage-A chunks/head; partial = 16 MB
#define ROWS_PER_CH (NROWS / NCH)     // 128
#define ROWS_PER_WV (ROWS_PER_CH / 4) // 32

// ---- Stage A: partial[bh][ch] = sum_{m in slice} K[m]^T (V[m]*x[m]) ----
// grid (NCH, BH) = 1024 blocks. Wave-private contiguous 32-row slice; 8x8
// per-thread register tile; K/V stream from global (8-lane broadcast float4,
// every byte read once device-wide); zero LDS in hot loop; unroll 4 for
// 16 loads in flight. Fixed-order cross-wave LDS reduce tail.
__global__ __launch_bounds__(256) void popattn_kv(
    const float* __restrict__ K, const float* __restrict__ V,
    const float* __restrict__ x, float* __restrict__ partial) {
  const int ch = blockIdx.x;
  const int bh = blockIdx.y;
  const float* Kp = K + (size_t)bh * (NROWS * DIM);
  const float* Vp = V + (size_t)bh * (NROWS * DIM);
  const float* xp = x + (size_t)(bh >> 4) * NROWS;  // x is [B,1,N,1], b = bh/16

  const int t = threadIdx.x;
  const int wv = t >> 6;          // wave id 0..3
  const int l = t & 63;
  const int ti = (l >> 3) << 3;   // 8x8 tile row base (K column block)
  const int tj = (l & 7) << 3;    // 8x8 tile col base (V column block)

  const int mstart = ch * ROWS_PER_CH + wv * ROWS_PER_WV;
  // lane L holds x[mstart + (L&31)]; broadcast per-m via __shfl.
  const float xall = xp[mstart + (l & 31)];

  float acc[8][8];
#pragma unroll
  for (int i = 0; i < 8; ++i)
#pragma unroll
    for (int j = 0; j < 8; ++j) acc[i][j] = 0.f;

#pragma unroll 4
  for (int mi = 0; mi < ROWS_PER_WV; ++mi) {
    const int m = mstart + mi;
    const float4 k0 = *(const float4*)(Kp + (size_t)m * DIM + ti);
    const float4 k1 = *(const float4*)(Kp + (size_t)m * DIM + ti + 4);
    const float4 v0 = *(const float4*)(Vp + (size_t)m * DIM + tj);
    const float4 v1 = *(const float4*)(Vp + (size_t)m * DIM + tj + 4);
    const float xv = __shfl(xall, mi);
    const float kk[8] = {k0.x, k0.y, k0.z, k0.w, k1.x, k1.y, k1.z, k1.w};
    float vw[8] = {v0.x, v0.y, v0.z, v0.w, v1.x, v1.y, v1.z, v1.w};
#pragma unroll
    for (int j = 0; j < 8; ++j) vw[j] *= xv;
#pragma unroll
    for (int i = 0; i < 8; ++i)
#pragma unroll
      for (int j = 0; j < 8; ++j) acc[i][j] += kk[i] * vw[j];
  }

  // ---- cross-wave reduce in LDS, fixed order s=0..3 (deterministic) ----
  __shared__ float smem[DIM * DIM];  // 16 KB
#pragma unroll 1
  for (int s = 0; s < 4; ++s) {
    if (wv == s) {
#pragma unroll
      for (int ii = 0; ii < 8; ++ii) {
        float* dst = &smem[(ti + ii) * DIM + tj];
        if (s == 0) {
          float4 o;
          o.x = acc[ii][0]; o.y = acc[ii][1]; o.z = acc[ii][2]; o.w = acc[ii][3];
          *(float4*)dst = o;
          o.x = acc[ii][4]; o.y = acc[ii][5]; o.z = acc[ii][6]; o.w = acc[ii][7];
          *(float4*)(dst + 4) = o;
        } else {
          float4 a = *(float4*)dst;
          a.x += acc[ii][0]; a.y += acc[ii][1]; a.z += acc[ii][2]; a.w += acc[ii][3];
          *(float4*)dst = a;
          a = *(float4*)(dst + 4);
          a.x += acc[ii][4]; a.y += acc[ii][5]; a.z += acc[ii][6]; a.w += acc[ii][7];
          *(float4*)(dst + 4) = a;
        }
      }
    }
    __syncthreads();
  }

  float* Pp = partial + ((size_t)bh * NCH + ch) * (DIM * DIM);
#pragma unroll
  for (int i = 0; i < 4; ++i) {
    const int idx = (t + 256 * i) * 4;
    *(float4*)(Pp + idx) = *(const float4*)&smem[idx];
  }
}

// ---- Stage A2: M[bh] = (sum_c partial[bh][c]) * 0.125, fixed order ----
__global__ __launch_bounds__(256) void popattn_red(
    const float* __restrict__ partial, float* __restrict__ M) {
  const int e = blockIdx.x;   // 0..3 quarter of the 64x64 matrix
  const int bh = blockIdx.y;
  const int off = e * 1024 + threadIdx.x * 4;
  const float* Pp = partial + (size_t)bh * NCH * (DIM * DIM);
  float sx = 0.f, sy = 0.f, sz = 0.f, sw = 0.f;
#pragma unroll
  for (int c = 0; c < NCH; ++c) {
    const float4 p = *(const float4*)(Pp + (size_t)c * (DIM * DIM) + off);
    sx += p.x; sy += p.y; sz += p.z; sw += p.w;
  }
  float4 o;
  o.x = sx * 0.125f; o.y = sy * 0.125f; o.z = sz * 0.125f; o.w = sw * 0.125f;
  *(float4*)(M + (size_t)bh * (DIM * DIM) + off) = o;
}

// ---- Stage B: out[bh] = Q[bh] @ M[bh] ----
// EXACT R2 body (part of the 44.2us best): 64 rows/block -> grid (32,BH) =
// 2048 blocks; per thread rows (r0, r0+32) x cols (c4..c4+3, c4+32..c4+35) =
// 16 acc VGPRs. Many blocks + small tile = occupancy hides Q latency.
__global__ __launch_bounds__(256) void popattn_qm(
    const float* __restrict__ Q, const float* __restrict__ M,
    float* __restrict__ out) {
  const int ch = blockIdx.x;  // 0..31
  const int bh = blockIdx.y;
  const int row0 = ch * 64;
  const float* Qp = Q + (size_t)bh * (NROWS * DIM) + (size_t)row0 * DIM;
  float* Op = out + (size_t)bh * (NROWS * DIM) + (size_t)row0 * DIM;

  __shared__ float sM[DIM * DIM];  // 16 KB

  const int t = threadIdx.x;
  {
    const float* Mp = M + (size_t)bh * (DIM * DIM);
#pragma unroll
    for (int i = 0; i < 4; ++i) {
      const int off = i * 1024 + t * 4;
      *(float4*)&sM[off] = *(const float4*)(Mp + off);
    }
  }
  __syncthreads();

  const int r0 = t >> 3;        // 0..31 (also owns r0+32)
  const int c4 = (t & 7) * 4;   // 0..28 (also owns c4+32)

  float a00 = 0.f, a01 = 0.f, a02 = 0.f, a03 = 0.f;  // row r0,   cols c4..
  float a04 = 0.f, a05 = 0.f, a06 = 0.f, a07 = 0.f;  // row r0,   cols c4+32..
  float a10 = 0.f, a11 = 0.f, a12 = 0.f, a13 = 0.f;  // row r0+32, cols c4..
  float a14 = 0.f, a15 = 0.f, a16 = 0.f, a17 = 0.f;  // row r0+32, cols c4+32..

#pragma unroll
  for (int kg = 0; kg < 16; ++kg) {
    const float4 qa = *(const float4*)(Qp + (size_t)r0 * DIM + kg * 4);
    const float4 qb = *(const float4*)(Qp + (size_t)(r0 + 32) * DIM + kg * 4);
    const float qav[4] = {qa.x, qa.y, qa.z, qa.w};
    const float qbv[4] = {qb.x, qb.y, qb.z, qb.w};
#pragma unroll
    for (int dk = 0; dk < 4; ++dk) {
      const int k = kg * 4 + dk;
      const float4 m0 = *(const float4*)&sM[k * DIM + c4];
      const float4 m1 = *(const float4*)&sM[k * DIM + c4 + 32];
      const float q0 = qav[dk], q1 = qbv[dk];
      a00 += q0 * m0.x; a01 += q0 * m0.y; a02 += q0 * m0.z; a03 += q0 * m0.w;
      a04 += q0 * m1.x; a05 += q0 * m1.y; a06 += q0 * m1.z; a07 += q0 * m1.w;
      a10 += q1 * m0.x; a11 += q1 * m0.y; a12 += q1 * m0.z; a13 += q1 * m0.w;
      a14 += q1 * m1.x; a15 += q1 * m1.y; a16 += q1 * m1.z; a17 += q1 * m1.w;
    }
  }

  float4 o;
  o.x = a00; o.y = a01; o.z = a02; o.w = a03;
  *(float4*)(Op + (size_t)r0 * DIM + c4) = o;
  o.x = a04; o.y = a05; o.z = a06; o.w = a07;
  *(float4*)(Op + (size_t)r0 * DIM + c4 + 32) = o;
  o.x = a10; o.y = a11; o.z = a12; o.w = a13;
  *(float4*)(Op + (size_t)(r0 + 32) * DIM + c4) = o;
  o.x = a14; o.y = a15; o.z = a16; o.w = a17;
  *(float4*)(Op + (size_t)(r0 + 32) * DIM + c4 + 32) = o;
}

extern "C" void kernel_launch(void* const* d_in, const int* in_sizes, int n_in,
                              void* d_out, int out_size, void* d_ws, size_t ws_size,
                              hipStream_t stream) {
  const float* Q = (const float*)d_in[0];
  const float* K = (const float*)d_in[1];
  const float* V = (const float*)d_in[2];
  const float* x = (const float*)d_in[3];
  float* out = (float*)d_out;
  float* partial = (float*)d_ws;  // BH*NCH*4096 floats = 16 MB
  float* Mbuf = partial + (size_t)BH * NCH * DIM * DIM;  // +1 MB

  dim3 blk(256);
  popattn_kv<<<dim3(NCH, BH), blk, 0, stream>>>(K, V, x, partial);
  popattn_red<<<dim3(4, BH), blk, 0, stream>>>(partial, Mbuf);
  popattn_qm<<<dim3(NROWS / 64, BH), blk, 0, stream>>>(Q, Mbuf, out);
}